// Round 1
// baseline (286.004 us; speedup 1.0000x reference)
//
#include <hip/hip_runtime.h>
#include <math.h>

#define D 64

typedef __fp16 fp16x2 __attribute__((ext_vector_type(2)));
typedef _Float16 half8 __attribute__((ext_vector_type(8)));
typedef _Float16 half4v __attribute__((ext_vector_type(4)));
typedef __attribute__((ext_vector_type(4))) float f32x4;

union h8pun { half8 v; fp16x2 h2[4]; };

// ---------------------------------------------------------------------------
// Prep: W1at/W1bt transposes, permuted fp16 W2h, segment boundaries.
// W2h[n][pos] = fp16(W2[pi_inv(pos)][n]),  pi_inv(pos) = (pos>>2) + 16*(pos&3).
// (q/p are stored with cols permuted by pi(col m+16t)=m*4+t; W2h compensates.)
__global__ __launch_bounds__(256) void k_prep(const float* __restrict__ W1,
                                              const float* __restrict__ W2,
                                              float* __restrict__ W1at,
                                              float* __restrict__ W1bt,
                                              _Float16* __restrict__ W2h,
                                              const int* __restrict__ seg_ids,
                                              int* __restrict__ start, int E, int N) {
    int i = blockIdx.x * 256 + threadIdx.x;
    if (i < 3 * D * D) {
        int mat = i / (D * D), j = i % (D * D);
        if (mat == 0) {
            int r = j >> 6, c = j & 63;
            W1at[c * D + r] = W1[r * D + c];
        } else if (mat == 1) {
            int r = j >> 6, c = j & 63;
            W1bt[c * D + r] = W1[(D + r) * D + c];
        } else {
            int n = j >> 6, pos = j & 63;
            int k = (pos >> 2) + 16 * (pos & 3);   // pi_inv
            W2h[n * D + pos] = (_Float16)W2[k * D + n];
        }
    }
    if (i <= N) {
        int lo = 0, hi = E;
        while (lo < hi) {
            int mid = (lo + hi) >> 1;
            if (seg_ids[mid] < i) lo = mid + 1; else hi = mid;
        }
        start[i] = lo;
    }
}

// ---------------------------------------------------------------------------
// Combined MFMA row-projection (fp16), both passes in one launch.
// Waves [0, wavesU):     q~[r] = pi(u2e[r] @ W1a), u2e_h[r] = fp16(u2e[r])
// Waves [wavesU, ...):   p~[r] = pi(u2e[nodes[r]] @ W1b + b1)
// pi-layout store: lane writes one contiguous half4 per row (coalesced 128 B).
__global__ __launch_bounds__(256) void k_proj_both(const float* __restrict__ u2e,
                                                   const int* __restrict__ nodes,
                                                   const float* __restrict__ W1at,
                                                   const float* __restrict__ W1bt,
                                                   const float* __restrict__ b1,
                                                   _Float16* __restrict__ q,
                                                   _Float16* __restrict__ u2e_h,
                                                   _Float16* __restrict__ p,
                                                   int U, int N, int wavesU, int wavesN) {
    int lane = threadIdx.x & 63;
    int m = lane & 15, quad = lane >> 4;
    int wave = (blockIdx.x * blockDim.x + threadIdx.x) >> 6;

    const float* Wt;
    const int* idx;
    const float* bias;
    _Float16* outp;
    _Float16* copyp;
    int R, w0, wstride;
    if (wave < wavesU) {
        Wt = W1at; idx = nullptr; bias = nullptr; outp = q; copyp = u2e_h;
        R = U; w0 = wave; wstride = wavesU;
    } else {
        Wt = W1bt; idx = nodes; bias = b1; outp = p; copyp = nullptr;
        R = N; w0 = wave - wavesU; wstride = wavesN;
    }

    half8 Bf[2][4];
    float bv[4];
#pragma unroll
    for (int t = 0; t < 4; ++t) {
        int n = m + 16 * t;
        bv[t] = bias ? bias[n] : 0.0f;
#pragma unroll
        for (int kh = 0; kh < 2; ++kh) {
            const float* col = Wt + n * D + kh * 32 + quad * 8;
#pragma unroll
            for (int j = 0; j < 8; ++j) Bf[kh][t][j] = (_Float16)col[j];
        }
    }

    int ngroups = (R + 15) / 16;
    for (int g = w0; g < ngroups; g += wstride) {
        int r_ = g * 16 + m;
        int rs = r_ < R ? r_ : R - 1;
        int src = idx ? idx[rs] : rs;
        const float4* arow = (const float4*)(u2e + (size_t)src * D);
        float4 x0 = arow[quad * 2], x1 = arow[quad * 2 + 1];
        float4 y0 = arow[8 + quad * 2], y1 = arow[8 + quad * 2 + 1];
        h8pun A0, A1;
        A0.h2[0] = __builtin_amdgcn_cvt_pkrtz(x0.x, x0.y);
        A0.h2[1] = __builtin_amdgcn_cvt_pkrtz(x0.z, x0.w);
        A0.h2[2] = __builtin_amdgcn_cvt_pkrtz(x1.x, x1.y);
        A0.h2[3] = __builtin_amdgcn_cvt_pkrtz(x1.z, x1.w);
        A1.h2[0] = __builtin_amdgcn_cvt_pkrtz(y0.x, y0.y);
        A1.h2[1] = __builtin_amdgcn_cvt_pkrtz(y0.z, y0.w);
        A1.h2[2] = __builtin_amdgcn_cvt_pkrtz(y1.x, y1.y);
        A1.h2[3] = __builtin_amdgcn_cvt_pkrtz(y1.z, y1.w);
        if (copyp && r_ < R) {
            *(half8*)(copyp + (size_t)r_ * D + quad * 8) = A0.v;
            *(half8*)(copyp + (size_t)r_ * D + 32 + quad * 8) = A1.v;
        }
        f32x4 C[4];
#pragma unroll
        for (int t = 0; t < 4; ++t) C[t] = (f32x4){bv[t], bv[t], bv[t], bv[t]};
#pragma unroll
        for (int t = 0; t < 4; ++t) {
            C[t] = __builtin_amdgcn_mfma_f32_16x16x32_f16(A0.v, Bf[0][t], C[t], 0, 0, 0);
            C[t] = __builtin_amdgcn_mfma_f32_16x16x32_f16(A1.v, Bf[1][t], C[t], 0, 0, 0);
        }
        // pi-layout store: position m*4+t holds col m+16t -> one half4 per row.
#pragma unroll
        for (int r = 0; r < 4; ++r) {
            int row = g * 16 + quad * 4 + r;
            if (row < R) {
                half4v hv = {(_Float16)C[0][r], (_Float16)C[1][r],
                             (_Float16)C[2][r], (_Float16)C[3][r]};
                *(half4v*)(outp + (size_t)row * D + m * 4) = hv;
            }
        }
    }
}

// ---------------------------------------------------------------------------
// Fused per-node kernel: edge logits (fp16 MFMA) + online softmax + weighted
// aggregation, one wave per node.  Replaces k_edge_logits_mfma + k_agg:
//  - q[nbr] gather and u2e_h[nbr] gather overlap in one kernel (both latency-
//    bound passes previously ran back-to-back)
//  - logits never round-trip through HBM
//  - p row loaded once per node instead of once per edge
// Batch of 16 edges per iteration: MFMA gives logits (C row = local edge
// quad*4+r, col = feature m+16t); reduce over m; online max/denom update;
// then 2 aggregation rounds of 8 edges (grp=lane>>3 edge, sub=lane&7 features).
__global__ __launch_bounds__(256) void k_fused(const int* __restrict__ nodes,
                                               const int* __restrict__ neigh_idx,
                                               const float* __restrict__ u2e,
                                               const _Float16* __restrict__ u2e_h,
                                               const _Float16* __restrict__ q,
                                               const _Float16* __restrict__ p,
                                               const _Float16* __restrict__ W2h,
                                               const float* __restrict__ b2,
                                               const float* __restrict__ w3,
                                               const float* __restrict__ b3,
                                               const int* __restrict__ start,
                                               float* __restrict__ out, int N) {
    int n = blockIdx.x * 4 + ((int)threadIdx.x >> 6);
    int lane = threadIdx.x & 63;
    if (n >= N) return;
    int s = start[n];
    int t = start[n + 1];
    if (s == t) {  // no neighbors: own embedding (fp32, exact)
        int node = nodes[n];
        out[(size_t)n * D + lane] = u2e[(size_t)node * D + lane];
        return;
    }
    int m = lane & 15, quad = lane >> 4;

    // W2 fragments (fp16, pre-permuted) + biases
    half8 Bf[2][4];
    float b2v[4], w3v[4];
#pragma unroll
    for (int tt = 0; tt < 4; ++tt) {
        int nn = m + 16 * tt;
        b2v[tt] = b2[nn];
        w3v[tt] = w3[nn];
        Bf[0][tt] = *(const half8*)(W2h + nn * D + quad * 8);
        Bf[1][tt] = *(const half8*)(W2h + nn * D + 32 + quad * 8);
    }
    float b3v = b3[0];
    const half8 hz = {0, 0, 0, 0, 0, 0, 0, 0};

    // p row for this node (pi layout, same as q)
    const half8* pr = (const half8*)(p + (size_t)n * D);
    half8 p0 = pr[quad], p1 = pr[quad + 4];

    int grp = lane >> 3, sub = lane & 7;   // aggregation roles
    float m_run = -INFINITY, denom = 0.0f;
    float acc[8];
#pragma unroll
    for (int j = 0; j < 8; ++j) acc[j] = 0.0f;

    int cnt = t - s;
    // prefetch first batch's neighbor index
    int nbr = neigh_idx[s + (m < cnt ? m : 0)];
    for (int b0 = 0; b0 < cnt; b0 += 16) {
        int nbr_c = nbr;
        const half8* qr = (const half8*)(q + (size_t)nbr_c * D);
        half8 q0 = qr[quad], q1 = qr[quad + 4];
        // prefetch next batch's neighbor index (hide idx-load latency under MFMA)
        if (b0 + 16 < cnt) {
            int nx = b0 + 16 + m;
            nbr = neigh_idx[s + (nx < cnt ? nx : 0)];
        }
        half8 A0 = __builtin_elementwise_max(q0 + p0, hz);
        half8 A1 = __builtin_elementwise_max(q1 + p1, hz);
        f32x4 C[4];
#pragma unroll
        for (int tt = 0; tt < 4; ++tt) C[tt] = (f32x4){b2v[tt], b2v[tt], b2v[tt], b2v[tt]};
#pragma unroll
        for (int tt = 0; tt < 4; ++tt) {
            C[tt] = __builtin_amdgcn_mfma_f32_16x16x32_f16(A0, Bf[0][tt], C[tt], 0, 0, 0);
            C[tt] = __builtin_amdgcn_mfma_f32_16x16x32_f16(A1, Bf[1][tt], C[tt], 0, 0, 0);
        }
        // per-lane partial logits (features m+16t), reduce over m-group
        float pa[4];
#pragma unroll
        for (int r = 0; r < 4; ++r) {
            float sa = 0.0f;
#pragma unroll
            for (int tt = 0; tt < 4; ++tt) sa += fmaxf(C[tt][r], 0.0f) * w3v[tt];
            pa[r] = sa;
        }
#pragma unroll
        for (int off = 1; off <= 8; off <<= 1) {
#pragma unroll
            for (int r = 0; r < 4; ++r) pa[r] += __shfl_xor(pa[r], off, 64);
        }
        // pa[r] = logit of local edge quad*4+r (all m-lanes agree); mask tail
#pragma unroll
        for (int r = 0; r < 4; ++r) {
            pa[r] += b3v;
            if (b0 + quad * 4 + r >= cnt) pa[r] = -INFINITY;
        }
        // batch max over the 16 edges (across quads; no m-overcount issues)
        float bm = fmaxf(fmaxf(pa[0], pa[1]), fmaxf(pa[2], pa[3]));
        bm = fmaxf(bm, __shfl_xor(bm, 16, 64));
        bm = fmaxf(bm, __shfl_xor(bm, 32, 64));
        float mn = fmaxf(m_run, bm);
        float scale = __expf(m_run - mn);   // first batch: exp(-inf)=0
        float sb = __expf(pa[0] - mn) + __expf(pa[1] - mn) +
                   __expf(pa[2] - mn) + __expf(pa[3] - mn);
        sb += __shfl_xor(sb, 16, 64);
        sb += __shfl_xor(sb, 32, 64);
        denom = denom * scale + sb;
#pragma unroll
        for (int j = 0; j < 8; ++j) acc[j] *= scale;
        m_run = mn;
        // aggregation: 2 rounds of 8 edges; lane (grp,sub) handles features
        // sub*8..sub*8+7 of local edge rd*8+grp
#pragma unroll
        for (int rd = 0; rd < 2; ++rd) {
            int le = rd * 8 + grp;
            int src = (le >> 2) << 4;           // lane holding pa for this quad-of-edges
            float t0 = __shfl(pa[0], src, 64);
            float t1 = __shfl(pa[1], src, 64);
            float t2 = __shfl(pa[2], src, 64);
            float t3 = __shfl(pa[3], src, 64);
            int rs = le & 3;
            float l = rs == 0 ? t0 : rs == 1 ? t1 : rs == 2 ? t2 : t3;
            int nb = __shfl(nbr_c, le, 64);     // lane le (quad 0, m=le) has edge le's nbr
            float w = __expf(l - mn);           // 0 for masked tail edges
            half8 r8 = *(const half8*)(u2e_h + (size_t)nb * D + sub * 8);
#pragma unroll
            for (int j = 0; j < 8; ++j) acc[j] += w * (float)r8[j];
        }
    }
    float inv = 1.0f / denom;
#pragma unroll
    for (int off = 8; off <= 32; off <<= 1) {
#pragma unroll
        for (int j = 0; j < 8; ++j) acc[j] += __shfl_xor(acc[j], off, 64);
    }
    if (grp == 0) {
        float* o = out + (size_t)n * D + sub * 8;
        *(float4*)o = make_float4(acc[0] * inv, acc[1] * inv, acc[2] * inv, acc[3] * inv);
        *(float4*)(o + 4) = make_float4(acc[4] * inv, acc[5] * inv, acc[6] * inv, acc[7] * inv);
    }
}

// ---------------------------------------------------------------------------
extern "C" void kernel_launch(void* const* d_in, const int* in_sizes, int n_in,
                              void* d_out, int out_size, void* d_ws, size_t ws_size,
                              hipStream_t stream) {
    const int* nodes = (const int*)d_in[0];
    const int* neigh_idx = (const int*)d_in[1];
    const int* seg_ids = (const int*)d_in[2];
    const float* u2e = (const float*)d_in[3];
    const float* W1 = (const float*)d_in[4];
    const float* b1 = (const float*)d_in[5];
    const float* W2 = (const float*)d_in[6];
    const float* b2 = (const float*)d_in[7];
    const float* w3 = (const float*)d_in[8];
    const float* b3 = (const float*)d_in[9];
    float* out = (float*)d_out;

    int N = in_sizes[0];
    int E = in_sizes[1];
    int U = in_sizes[3] / D;

    char* ws = (char*)d_ws;
    size_t off = 0;
    auto alloc = [&](size_t bytes) {
        void* ptr = ws + off;
        off = (off + bytes + 255) & ~(size_t)255;
        return ptr;
    };
    int* start = (int*)alloc((size_t)(N + 1) * 4);
    float* W1at = (float*)alloc((size_t)D * D * 4);
    float* W1bt = (float*)alloc((size_t)D * D * 4);
    _Float16* W2h = (_Float16*)alloc((size_t)D * D * 2);
    _Float16* q = (_Float16*)alloc((size_t)U * D * 2);
    _Float16* p = (_Float16*)alloc((size_t)N * D * 2);
    _Float16* u2e_h = (_Float16*)alloc((size_t)U * D * 2);
    (void)ws_size;

    int prep_n = (N + 1) > 3 * D * D ? (N + 1) : 3 * D * D;
    k_prep<<<(prep_n + 255) / 256, 256, 0, stream>>>(W1, W2, W1at, W1bt, W2h,
                                                     seg_ids, start, E, N);
    const int wavesU = 4096, wavesN = 1024;
    k_proj_both<<<(wavesU + wavesN) / 4, 256, 0, stream>>>(u2e, nodes, W1at, W1bt, b1,
                                                           q, u2e_h, p, U, N, wavesU, wavesN);
    k_fused<<<(N + 3) / 4, 256, 0, stream>>>(nodes, neigh_idx, u2e, u2e_h, q, p,
                                             W2h, b2, w3, b3, start, out, N);
}